// Round 4
// baseline (317.770 us; speedup 1.0000x reference)
//
#include <hip/hip_runtime.h>
#include <hip/hip_bf16.h>

#define BB 8
#define NN 2048
#define DD 128

typedef __attribute__((ext_vector_type(8))) __bf16 bf16x8;
typedef __attribute__((ext_vector_type(4))) float f32x4;
typedef __attribute__((ext_vector_type(4))) int   i32x4;

static __device__ __forceinline__ unsigned short f2bf(float f) {
    union { float f; unsigned u; } v; v.f = f;
    unsigned r = (v.u + 0x7FFFu + ((v.u >> 16) & 1u)) >> 16;
    return (unsigned short)r;
}
static __device__ __forceinline__ float bf2f(unsigned short b) {
    union { unsigned u; float f; } v; v.u = ((unsigned)b) << 16;
    return v.f;
}

// ---------------------------------------------------------------------------
// kernP: blocks 0..4095 pack Ptilde bits + scale/pdm (proven in R3).
// Block 4096 casts combined weights Wc[e][k] (k<128: w_self, else w_punct)
// to bf16 (64 KB), used by kernE phase 2.
// ---------------------------------------------------------------------------
__global__ __launch_bounds__(256) void kernP(
    const int* __restrict__ punct, const int* __restrict__ mask,
    const float* __restrict__ w_self, const float* __restrict__ w_punct,
    unsigned* __restrict__ pk, float* __restrict__ scale_g, float* __restrict__ pdm_g,
    unsigned short* __restrict__ wc)
{
    const int t = threadIdx.x;
    if (blockIdx.x == 4096) {
        for (int idx = t; idx < 128 * 256; idx += 256) {
            const int e = idx >> 8, k = idx & 255;
            const float v = (k < 128) ? w_self[e * 128 + k]
                                      : w_punct[e * 128 + (k - 128)];
            wc[idx] = f2bf(v);
        }
        return;
    }
    const int wave = t >> 6, lane = t & 63;
    const int row_g = blockIdx.x * 4 + wave;
    const int b = row_g >> 11;
    const int i = row_g & (NN - 1);

    const int* prow = punct + (size_t)row_g * NN;
    const int* mrow = mask + (size_t)b * NN;

    unsigned pk0 = 0, pk1 = 0;
    int acc = 0;
    #pragma unroll 4
    for (int w = 0; w < 32; ++w) {
        const int col = w * 64 + lane;
        const int pred = (prow[col] & mrow[col]) & 1;
        unsigned long long bal = __ballot(pred);
        if (lane == w) { pk0 = (unsigned)bal; pk1 = (unsigned)(bal >> 32); }
        acc += pred + ((col == i ? pred : 0) << 16);
    }
    #pragma unroll
    for (int o = 32; o > 0; o >>= 1) acc += __shfl_xor(acc, o, 64);

    if (lane < 32) {                     // lanes 32..63 hold no ballots (R2 bug)
        uint2 w2; w2.x = pk0; w2.y = pk1;
        *(uint2*)(pk + (size_t)row_g * 64 + 2 * lane) = w2;
    }
    if (lane == 0) {
        const int nall = acc & 0xFFFF;
        const int pdm  = acc >> 16;
        const int mi   = mrow[i];
        const int nbr  = nall - pdm;
        scale_g[row_g] = mi ? 1.f / (float)(nbr < 1 ? 1 : nbr) : 0.f;
        pdm_g[row_g]   = (float)pdm;
    }
}

// ---------------------------------------------------------------------------
// kernD (step-0 prologue): dw0 = sigmoid(x.w_nw + b_nw); writes aw[:,0,:],
// xbf (bf16 x row-major), xw = dw*x (bf16 row-major), xwT ([B][D][N]).
// 64 rows/block; thread t -> (row=t>>2, quarter q=t&3, 32 cols).
// ---------------------------------------------------------------------------
__global__ __launch_bounds__(256) void kernD(
    const float* __restrict__ x,
    const float* __restrict__ w_nw, const float* __restrict__ b_nw,
    float* __restrict__ aw_out,
    unsigned short* __restrict__ xbf, unsigned short* __restrict__ xw,
    unsigned short* __restrict__ xwT)
{
    __shared__ float wnw_l[DD];
    __shared__ float red[256];
    __shared__ float dw_l[64];
    __shared__ unsigned short xl[64 * 136];

    const int t  = threadIdx.x;
    const int n0 = blockIdx.x * 64;
    const int b  = n0 >> 11;
    const int nb = n0 & (NN - 1);

    if (t < DD) wnw_l[t] = w_nw[t];
    __syncthreads();

    const int row = t >> 2, q = t & 3;
    const float* xs = x + (size_t)(n0 + row) * DD + q * 32;
    float vals[32];
    float dp = 0.f;
    #pragma unroll
    for (int j = 0; j < 8; ++j) {
        f32x4 a = *(const f32x4*)(xs + j * 4);
        vals[j*4+0] = a.x; vals[j*4+1] = a.y; vals[j*4+2] = a.z; vals[j*4+3] = a.w;
        const float* wv = &wnw_l[q * 32 + j * 4];
        dp += a.x*wv[0] + a.y*wv[1] + a.z*wv[2] + a.w*wv[3];
    }
    red[t] = dp;
    __syncthreads();
    if (t < 64) {
        float s = red[4*t] + red[4*t+1] + red[4*t+2] + red[4*t+3] + b_nw[0];
        float dv = 1.f / (1.f + __expf(-s));
        dw_l[t] = dv;
        aw_out[(size_t)b * 2 * NN + nb + t] = dv;
    }
    __syncthreads();

    // xbf row-major
    unsigned pb[16];
    #pragma unroll
    for (int j = 0; j < 16; ++j)
        pb[j] = f2bf(vals[2*j]) | ((unsigned)f2bf(vals[2*j+1]) << 16);
    {
        i32x4* dst = (i32x4*)(xbf + (size_t)(n0 + row) * DD + q * 32);
        i32x4 v0 = {(int)pb[0],(int)pb[1],(int)pb[2],(int)pb[3]};
        i32x4 v1 = {(int)pb[4],(int)pb[5],(int)pb[6],(int)pb[7]};
        i32x4 v2 = {(int)pb[8],(int)pb[9],(int)pb[10],(int)pb[11]};
        i32x4 v3 = {(int)pb[12],(int)pb[13],(int)pb[14],(int)pb[15]};
        dst[0]=v0; dst[1]=v1; dst[2]=v2; dst[3]=v3;
    }
    // xw row-major + LDS tile for transpose
    const float dwv = dw_l[row];
    #pragma unroll
    for (int j = 0; j < 16; ++j)
        pb[j] = f2bf(vals[2*j]*dwv) | ((unsigned)f2bf(vals[2*j+1]*dwv) << 16);
    {
        i32x4 v0 = {(int)pb[0],(int)pb[1],(int)pb[2],(int)pb[3]};
        i32x4 v1 = {(int)pb[4],(int)pb[5],(int)pb[6],(int)pb[7]};
        i32x4 v2 = {(int)pb[8],(int)pb[9],(int)pb[10],(int)pb[11]};
        i32x4 v3 = {(int)pb[12],(int)pb[13],(int)pb[14],(int)pb[15]};
        i32x4* dst = (i32x4*)(xw + (size_t)(n0 + row) * DD + q * 32);
        dst[0]=v0; dst[1]=v1; dst[2]=v2; dst[3]=v3;
        i32x4* ld = (i32x4*)&xl[row * 136 + q * 32];
        ld[0]=v0; ld[1]=v1; ld[2]=v2; ld[3]=v3;
    }
    __syncthreads();
    // transposed writeout: thread t -> (d = t>>1, half = t&1), 32 rows
    {
        const int d = t >> 1, half = t & 1;
        unsigned o[16];
        #pragma unroll
        for (int k = 0; k < 16; ++k) {
            const int r0 = half * 32 + 2 * k;
            o[k] = (unsigned)xl[r0 * 136 + d] | ((unsigned)xl[(r0+1) * 136 + d] << 16);
        }
        i32x4 v0 = {(int)o[0],(int)o[1],(int)o[2],(int)o[3]};
        i32x4 v1 = {(int)o[4],(int)o[5],(int)o[6],(int)o[7]};
        i32x4 v2 = {(int)o[8],(int)o[9],(int)o[10],(int)o[11]};
        i32x4 v3 = {(int)o[12],(int)o[13],(int)o[14],(int)o[15]};
        i32x4* dst = (i32x4*)(xwT + (size_t)(b * DD + d) * NN + nb + half * 32);
        dst[0]=v0; dst[1]=v1; dst[2]=v2; dst[3]=v3;
    }
}

// ---------------------------------------------------------------------------
// kernE: fused GCN step.
//  phase 1: Z = bitP @ xwT  (R3-proven K-loop, zero barriers)
//           Zs = scale*(Z - pdm*xw_i)  -> LDS (bf16, [row][d])
//  phase 2: out = [xbf | Zs] @ Wc^T  (K=256), relu(+b_self)
//  epilogue: x_out (f32), dw_next -> aw_next, xbf/xw/xwT for next step.
// ---------------------------------------------------------------------------
__global__ __launch_bounds__(256) void kernE(
    const unsigned* __restrict__ pk,
    const float* __restrict__ scale_g, const float* __restrict__ pdm_g,
    const unsigned short* __restrict__ xwT,   // [B][D][N]
    const unsigned short* __restrict__ xw,    // [B*N][D]
    const unsigned short* __restrict__ xbf,   // [B*N][D]
    const unsigned short* __restrict__ wc,    // [128][256]
    const float* __restrict__ b_self,
    const float* __restrict__ w_nw, const float* __restrict__ b_nw,
    float* __restrict__ x_out, float* __restrict__ aw_next,
    unsigned short* __restrict__ xbf_o, unsigned short* __restrict__ xw_o,
    unsigned short* __restrict__ xwT_o)
{
    __shared__ unsigned pPk[64 * 68];         // phase1 bits; later reused as red[]
    __shared__ unsigned short ZsL[64 * 136];  // Zs, later x_new bf16
    __shared__ float scale_l[64], pdm_l[64], dw_l[64];

    const int t  = threadIdx.x;
    const int b  = blockIdx.x >> 5;
    const int i0 = (blockIdx.x & 31) * 64;
    const size_t rg0 = (size_t)b * NN + i0;

    #pragma unroll
    for (int r = 0; r < 4; ++r) {
        const int u = r * 256 + t;
        const int row = u >> 4;
        const int wq  = (u & 15) * 4;
        i32x4 v = *(const i32x4*)(pk + (rg0 + row) * 64 + wq);
        *(i32x4*)&pPk[row * 68 + wq] = v;
    }
    if (t < 64) {
        scale_l[t] = scale_g[rg0 + t];
        pdm_l[t]   = pdm_g[rg0 + t];
    }
    __syncthreads();

    const int wn = t >> 6, lane = t & 63;
    const int quad = lane >> 4, l16 = lane & 15;
    const unsigned short* xwTb = xwT + (size_t)b * DD * NN;

    // ---- phase 1: Z = bitP @ xwT ----
    f32x4 acc[4][2] = {};
    #pragma unroll 4
    for (int kk = 0; kk < 64; ++kk) {
        bf16x8 bfr[2];
        #pragma unroll
        for (int nt = 0; nt < 2; ++nt) {
            const int d = wn*32 + nt*16 + l16;
            bfr[nt] = *(const bf16x8*)(xwTb + (size_t)d * NN + kk*32 + quad*8);
        }
        bf16x8 af[4];
        #pragma unroll
        for (int mt = 0; mt < 4; ++mt) {
            const unsigned w = pPk[(mt*16 + l16) * 68 + kk];
            const unsigned by = (w >> (quad * 8)) & 0xFFu;
            i32x4 ex;
            ex.x = ((by &   1u) ? 0x3F80 : 0) | ((by &   2u) ? 0x3F800000 : 0);
            ex.y = ((by &   4u) ? 0x3F80 : 0) | ((by &   8u) ? 0x3F800000 : 0);
            ex.z = ((by &  16u) ? 0x3F80 : 0) | ((by &  32u) ? 0x3F800000 : 0);
            ex.w = ((by &  64u) ? 0x3F80 : 0) | ((by & 128u) ? 0x3F800000 : 0);
            union { i32x4 i; bf16x8 h; } cv; cv.i = ex;
            af[mt] = cv.h;
        }
        #pragma unroll
        for (int mt = 0; mt < 4; ++mt)
            #pragma unroll
            for (int nt = 0; nt < 2; ++nt)
                acc[mt][nt] = __builtin_amdgcn_mfma_f32_16x16x32_bf16(af[mt], bfr[nt], acc[mt][nt], 0, 0, 0);
    }

    // ---- Zs -> LDS ----
    #pragma unroll
    for (int mt = 0; mt < 4; ++mt) {
        #pragma unroll
        for (int nt = 0; nt < 2; ++nt) {
            const int d = wn*32 + nt*16 + l16;
            #pragma unroll
            for (int r = 0; r < 4; ++r) {
                const int row = mt*16 + quad*4 + r;
                const float xwv = bf2f(xw[(rg0 + row) * DD + d]);
                const float zs = scale_l[row] * (acc[mt][nt][r] - pdm_l[row] * xwv);
                ZsL[row * 136 + d] = f2bf(zs);
            }
        }
    }
    __syncthreads();

    // ---- phase 2: [xbf | Zs] @ Wc^T ----
    f32x4 acc2[4][2] = {};
    #pragma unroll
    for (int kq2 = 0; kq2 < 8; ++kq2) {
        bf16x8 b2[2];
        #pragma unroll
        for (int nt2 = 0; nt2 < 2; ++nt2) {
            const int e = wn*32 + nt2*16 + l16;
            b2[nt2] = *(const bf16x8*)(wc + (size_t)e * 256 + kq2*32 + quad*8);
        }
        bf16x8 a2[4];
        if (kq2 < 4) {
            #pragma unroll
            for (int mt = 0; mt < 4; ++mt)
                a2[mt] = *(const bf16x8*)(xbf + (rg0 + mt*16 + l16) * DD + kq2*32 + quad*8);
        } else {
            #pragma unroll
            for (int mt = 0; mt < 4; ++mt)
                a2[mt] = *(const bf16x8*)&ZsL[(mt*16 + l16) * 136 + (kq2-4)*32 + quad*8];
        }
        #pragma unroll
        for (int mt = 0; mt < 4; ++mt)
            #pragma unroll
            for (int nt2 = 0; nt2 < 2; ++nt2)
                acc2[mt][nt2] = __builtin_amdgcn_mfma_f32_16x16x32_bf16(a2[mt], b2[nt2], acc2[mt][nt2], 0, 0, 0);
    }
    __syncthreads();   // everyone done reading ZsL/pPk

    // ---- epilogue: relu, x_out, dw partials, x_new bf16 -> ZsL ----
    float bias[2], wnv[2];
    #pragma unroll
    for (int nt2 = 0; nt2 < 2; ++nt2) {
        const int e = wn*32 + nt2*16 + l16;
        bias[nt2] = b_self[e];
        wnv[nt2]  = w_nw[e];
    }
    float* red = (float*)pPk;   // [64][65]
    #pragma unroll
    for (int mt = 0; mt < 4; ++mt) {
        #pragma unroll
        for (int r = 0; r < 4; ++r) {
            const int row = mt*16 + quad*4 + r;
            float p = 0.f;
            #pragma unroll
            for (int nt2 = 0; nt2 < 2; ++nt2) {
                const int e = wn*32 + nt2*16 + l16;
                float v = fmaxf(acc2[mt][nt2][r] + bias[nt2], 0.f);
                acc2[mt][nt2][r] = v;
                x_out[(rg0 + row) * DD + e] = v;
                ZsL[row * 136 + e] = f2bf(v);
                p += v * wnv[nt2];
            }
            red[row * 65 + wn*16 + l16] = p;
        }
    }
    __syncthreads();
    if (t < 64) {
        float s = b_nw[0];
        #pragma unroll 8
        for (int c = 0; c < 64; ++c) s += red[t * 65 + c];
        float dv = 1.f / (1.f + __expf(-s));
        dw_l[t] = dv;
        aw_next[(size_t)b * 2 * NN + i0 + t] = dv;
    }
    __syncthreads();

    // ---- writeouts for next step ----
    {   // row-major xbf_o, xw_o
        const int row = t >> 2, q = t & 3;
        const i32x4* src = (const i32x4*)&ZsL[row * 136 + q * 32];
        i32x4 u0 = src[0], u1 = src[1], u2 = src[2], u3 = src[3];
        i32x4* db = (i32x4*)(xbf_o + (rg0 + row) * DD + q * 32);
        db[0]=u0; db[1]=u1; db[2]=u2; db[3]=u3;
        const float dwv = dw_l[row];
        unsigned uu[8] = {(unsigned)u0.x,(unsigned)u0.y,(unsigned)u0.z,(unsigned)u0.w,
                          (unsigned)u1.x,(unsigned)u1.y,(unsigned)u1.z,(unsigned)u1.w};
        unsigned vv[8] = {(unsigned)u2.x,(unsigned)u2.y,(unsigned)u2.z,(unsigned)u2.w,
                          (unsigned)u3.x,(unsigned)u3.y,(unsigned)u3.z,(unsigned)u3.w};
        unsigned o[16];
        #pragma unroll
        for (int j = 0; j < 8; ++j) {
            float lo = bf2f((unsigned short)(uu[j] & 0xFFFF)) * dwv;
            float hi = bf2f((unsigned short)(uu[j] >> 16)) * dwv;
            o[j] = f2bf(lo) | ((unsigned)f2bf(hi) << 16);
        }
        #pragma unroll
        for (int j = 0; j < 8; ++j) {
            float lo = bf2f((unsigned short)(vv[j] & 0xFFFF)) * dwv;
            float hi = bf2f((unsigned short)(vv[j] >> 16)) * dwv;
            o[8+j] = f2bf(lo) | ((unsigned)f2bf(hi) << 16);
        }
        i32x4 w0 = {(int)o[0],(int)o[1],(int)o[2],(int)o[3]};
        i32x4 w1 = {(int)o[4],(int)o[5],(int)o[6],(int)o[7]};
        i32x4 w2 = {(int)o[8],(int)o[9],(int)o[10],(int)o[11]};
        i32x4 w3 = {(int)o[12],(int)o[13],(int)o[14],(int)o[15]};
        i32x4* dw_ = (i32x4*)(xw_o + (rg0 + row) * DD + q * 32);
        dw_[0]=w0; dw_[1]=w1; dw_[2]=w2; dw_[3]=w3;
        // stash xw bf16 back into ZsL for the transposed writeout
        i32x4* lw = (i32x4*)&ZsL[row * 136 + q * 32];
        __syncthreads();   // all reads of x_new ZsL done before overwrite
        lw[0]=w0; lw[1]=w1; lw[2]=w2; lw[3]=w3;
    }
    __syncthreads();
    {   // transposed xwT_o
        const int d = t >> 1, half = t & 1;
        unsigned o[16];
        #pragma unroll
        for (int k = 0; k < 16; ++k) {
            const int r0 = half * 32 + 2 * k;
            o[k] = (unsigned)ZsL[r0 * 136 + d] | ((unsigned)ZsL[(r0+1) * 136 + d] << 16);
        }
        i32x4 v0 = {(int)o[0],(int)o[1],(int)o[2],(int)o[3]};
        i32x4 v1 = {(int)o[4],(int)o[5],(int)o[6],(int)o[7]};
        i32x4 v2 = {(int)o[8],(int)o[9],(int)o[10],(int)o[11]};
        i32x4 v3 = {(int)o[12],(int)o[13],(int)o[14],(int)o[15]};
        i32x4* dst = (i32x4*)(xwT_o + (size_t)(b * DD + d) * NN + i0 + half * 32);
        dst[0]=v0; dst[1]=v1; dst[2]=v2; dst[3]=v3;
    }
}

extern "C" void kernel_launch(void* const* d_in, const int* in_sizes, int n_in,
                              void* d_out, int out_size, void* d_ws, size_t ws_size,
                              hipStream_t stream) {
    const float* node   = (const float*)d_in[0];
    const int*   mask   = (const int*)  d_in[1];
    const int*   punct  = (const int*)  d_in[2];
    const float* w_nw   = (const float*)d_in[3];
    const float* b_nw   = (const float*)d_in[4];
    const float* w_self = (const float*)d_in[5];
    const float* b_self = (const float*)d_in[6];
    const float* w_punct= (const float*)d_in[7];

    float* xout = (float*)d_out;
    float* aw   = xout + (size_t)BB * NN * DD;

    char* w = (char*)d_ws;
    unsigned*       pk    = (unsigned*)w;                               // 4 MB
    float*          scl   = (float*)(w + (4u<<20));                     // 64 KB
    float*          pdm   = (float*)(w + (4u<<20) + (64u<<10));         // 64 KB
    unsigned short* wc    = (unsigned short*)(w + (4u<<20) + (128u<<10)); // 64 KB
    float*          awdum = (float*)(w + (4u<<20) + (192u<<10));        // 256 KB
    unsigned short* xbf0  = (unsigned short*)(w + (5u<<20));            // 4 MB
    unsigned short* xw0   = (unsigned short*)(w + (9u<<20));            // 4 MB
    unsigned short* xwT0  = (unsigned short*)(w + (13u<<20));           // 4 MB
    unsigned short* xbf1  = (unsigned short*)(w + (17u<<20));           // 4 MB
    unsigned short* xw1   = (unsigned short*)(w + (21u<<20));           // 4 MB
    unsigned short* xwT1  = (unsigned short*)(w + (25u<<20));           // 4 MB

    dim3 blk(256);
    kernP<<<dim3(4097), blk, 0, stream>>>(punct, mask, w_self, w_punct, pk, scl, pdm, wc);
    kernD<<<dim3(256), blk, 0, stream>>>(node, w_nw, b_nw, aw, xbf0, xw0, xwT0);
    // step 0: consumes step-0 tensors, produces x1 (d_out), dw1 (aw+NN), step-1 tensors
    kernE<<<dim3(256), blk, 0, stream>>>(pk, scl, pdm, xwT0, xw0, xbf0, wc, b_self,
                                         w_nw, b_nw, xout, aw + NN, xbf1, xw1, xwT1);
    // step 1: produces final x2 (d_out); dw2/next tensors go to dummy space
    kernE<<<dim3(256), blk, 0, stream>>>(pk, scl, pdm, xwT1, xw1, xbf1, wc, b_self,
                                         w_nw, b_nw, xout, awdum, xbf0, xw0, xwT0);
}